// Round 1
// baseline (1140.843 us; speedup 1.0000x reference)
//
#include <hip/hip_runtime.h>
#include <hip/hip_bf16.h>
#include <math.h>

#define HEADS 4
#define OUT_F 32
#define EDGE_F 16
#define ALPHA 0.2f
#define CF 128   // HEADS*OUT_F
#define IN_F 128

// ---------------------------------------------------------------------------
// Kernel 1: Wh = h @ W   (N x 128 @ 128 x 128), fused with per-node
// attention scalars  s_src[n,h] = dot(Wh[n,h,:], a[h,0:32])
//                    s_dst[n,h] = dot(Wh[n,h,:], a[h,32:64])
// One wave per row; lane owns cols {2l, 2l+1}; W staged in LDS.
// ---------------------------------------------------------------------------
__global__ void k_gemm_wh(const float* __restrict__ h,
                          const float* __restrict__ W,
                          const float* __restrict__ a,
                          float* __restrict__ Wh,
                          float* __restrict__ ssrc,
                          float* __restrict__ sdst,
                          int N)
{
    __shared__ float Ws[IN_F * CF];      // 64 KB
    __shared__ float aS[CF], aD[CF];

    int tid = threadIdx.x;
    // stage W (4096 float4, 256 threads -> 16 each)
    const float4* W4 = (const float4*)W;
    float4* Ws4 = (float4*)Ws;
    #pragma unroll
    for (int i = tid; i < (IN_F * CF) / 4; i += 256) Ws4[i] = W4[i];
    if (tid < CF) {
        int hh = tid >> 5, c = tid & 31;
        aS[tid] = a[hh * (2 * OUT_F + EDGE_F) + c];
        aD[tid] = a[hh * (2 * OUT_F + EDGE_F) + OUT_F + c];
    }
    __syncthreads();

    int wave = tid >> 6;
    int lane = tid & 63;
    int c0 = lane * 2;

    for (int r = blockIdx.x * 4 + wave; r < N; r += gridDim.x * 4) {
        const float* hr = h + (size_t)r * IN_F;
        float acc0 = 0.f, acc1 = 0.f;
        #pragma unroll 8
        for (int k = 0; k < IN_F; ++k) {
            float hv = hr[k];             // wave-uniform -> scalar load
            acc0 = fmaf(hv, Ws[k * CF + c0], acc0);
            acc1 = fmaf(hv, Ws[k * CF + c0 + 1], acc1);
        }
        *(float2*)(Wh + (size_t)r * CF + c0) = make_float2(acc0, acc1);

        float ps = acc0 * aS[c0] + acc1 * aS[c0 + 1];
        float pd = acc0 * aD[c0] + acc1 * aD[c0 + 1];
        // reduce within 16-lane group (one head per group)
        #pragma unroll
        for (int off = 1; off < 16; off <<= 1) {
            ps += __shfl_xor(ps, off);
            pd += __shfl_xor(pd, off);
        }
        if ((lane & 15) == 0) {
            int hh = lane >> 4;
            ssrc[(size_t)r * HEADS + hh] = ps;
            sdst[(size_t)r * HEADS + hh] = pd;
        }
    }
}

// ---------------------------------------------------------------------------
// Kernel 2: per-edge attention logits + leaky-relu + softmax over 4 heads.
// One thread per edge.
// ---------------------------------------------------------------------------
__global__ void k_att(const int* __restrict__ ei,
                      const float* __restrict__ ea,
                      const float* __restrict__ a,
                      const float* __restrict__ ssrc,
                      const float* __restrict__ sdst,
                      float* __restrict__ att,
                      int E)
{
    __shared__ float ae[HEADS][EDGE_F];
    int tid = threadIdx.x;
    if (tid < HEADS * EDGE_F) {
        int hh = tid >> 4, j = tid & 15;
        ae[hh][j] = a[hh * (2 * OUT_F + EDGE_F) + 2 * OUT_F + j];
    }
    __syncthreads();

    for (int e = blockIdx.x * blockDim.x + tid; e < E; e += gridDim.x * blockDim.x) {
        int s = ei[e];
        int d = ei[E + e];
        float4 es = *(const float4*)(ssrc + (size_t)s * HEADS);
        float4 ed = *(const float4*)(sdst + (size_t)d * HEADS);
        const float* eav = ea + (size_t)e * EDGE_F;
        float4 v0 = *(const float4*)(eav + 0);
        float4 v1 = *(const float4*)(eav + 4);
        float4 v2 = *(const float4*)(eav + 8);
        float4 v3 = *(const float4*)(eav + 12);

        float ev[HEADS];
        float base[HEADS] = {es.x + ed.x, es.y + ed.y, es.z + ed.z, es.w + ed.w};
        #pragma unroll
        for (int hh = 0; hh < HEADS; ++hh) {
            const float* av = ae[hh];
            float dotv = v0.x * av[0] + v0.y * av[1] + v0.z * av[2] + v0.w * av[3]
                       + v1.x * av[4] + v1.y * av[5] + v1.z * av[6] + v1.w * av[7]
                       + v2.x * av[8] + v2.y * av[9] + v2.z * av[10] + v2.w * av[11]
                       + v3.x * av[12] + v3.y * av[13] + v3.z * av[14] + v3.w * av[15];
            float x = base[hh] + dotv;
            ev[hh] = (x >= 0.f) ? x : ALPHA * x;
        }
        float m = fmaxf(fmaxf(ev[0], ev[1]), fmaxf(ev[2], ev[3]));
        float p0 = __expf(ev[0] - m), p1 = __expf(ev[1] - m);
        float p2 = __expf(ev[2] - m), p3 = __expf(ev[3] - m);
        float inv = 1.f / (p0 + p1 + p2 + p3);
        *(float4*)(att + (size_t)e * HEADS) =
            make_float4(p0 * inv, p1 * inv, p2 * inv, p3 * inv);
    }
}

// ---------------------------------------------------------------------------
// Kernel 3: scatter  h_prime[src] += att[e,h] * Wh[dst]
// 32 threads per edge, 4 channels per thread, fp32 HW atomics.
// ---------------------------------------------------------------------------
__global__ void k_scatter(const int* __restrict__ ei,
                          const float* __restrict__ att,
                          const float* __restrict__ Wh,
                          float* __restrict__ hp,
                          int E)
{
    long long gid = (long long)blockIdx.x * blockDim.x + threadIdx.x;
    int e = (int)(gid >> 5);
    if (e >= E) return;
    int q = (int)(gid & 31);
    int c = q * 4;
    int hh = c >> 5;

    int s = ei[e];
    int d = ei[E + e];
    float atv = att[(size_t)e * HEADS + hh];
    float4 wv = *(const float4*)(Wh + (size_t)d * CF + c);
    float* out = hp + (size_t)s * CF + c;
    unsafeAtomicAdd(out + 0, atv * wv.x);
    unsafeAtomicAdd(out + 1, atv * wv.y);
    unsafeAtomicAdd(out + 2, atv * wv.z);
    unsafeAtomicAdd(out + 3, atv * wv.w);
}

// ---------------------------------------------------------------------------
// Kernel 4: ELU epilogue
// ---------------------------------------------------------------------------
__global__ void k_elu(const float* __restrict__ hp, float* __restrict__ out, int n4)
{
    int i = blockIdx.x * blockDim.x + threadIdx.x;
    if (i < n4) {
        float4 v = ((const float4*)hp)[i];
        v.x = (v.x > 0.f) ? v.x : (__expf(v.x) - 1.f);
        v.y = (v.y > 0.f) ? v.y : (__expf(v.y) - 1.f);
        v.z = (v.z > 0.f) ? v.z : (__expf(v.z) - 1.f);
        v.w = (v.w > 0.f) ? v.w : (__expf(v.w) - 1.f);
        ((float4*)out)[i] = v;
    }
}

extern "C" void kernel_launch(void* const* d_in, const int* in_sizes, int n_in,
                              void* d_out, int out_size, void* d_ws, size_t ws_size,
                              hipStream_t stream)
{
    const float* h  = (const float*)d_in[0];
    const int*   ei = (const int*)d_in[1];
    const float* ea = (const float*)d_in[2];
    const float* W  = (const float*)d_in[3];
    const float* a  = (const float*)d_in[4];
    float* out = (float*)d_out;

    int N = in_sizes[0] / IN_F;     // 20000
    int E = in_sizes[1] / 2;        // 640000

    float* ws   = (float*)d_ws;
    float* Wh   = ws;                                // N*128
    float* ssrc = Wh   + (size_t)N * CF;             // N*4
    float* sdst = ssrc + (size_t)N * HEADS;          // N*4
    float* att  = sdst + (size_t)N * HEADS;          // E*4
    float* hp   = att  + (size_t)E * HEADS;          // N*128

    hipMemsetAsync(hp, 0, (size_t)N * CF * sizeof(float), stream);

    k_gemm_wh<<<1024, 256, 0, stream>>>(h, W, a, Wh, ssrc, sdst, N);
    k_att<<<(E + 255) / 256, 256, 0, stream>>>(ei, ea, a, ssrc, sdst, att, E);

    long long scatter_threads = (long long)E * 32;
    k_scatter<<<(int)((scatter_threads + 255) / 256), 256, 0, stream>>>(ei, att, Wh, hp, E);

    int n4 = N * CF / 4;
    k_elu<<<(n4 + 255) / 256, 256, 0, stream>>>(hp, out, n4);
}

// Round 2
// 222.833 us; speedup vs baseline: 5.1197x; 5.1197x over previous
//
#include <hip/hip_runtime.h>
#include <hip/hip_bf16.h>
#include <math.h>

#define HEADS 4
#define OUT_F 32
#define EDGE_F 16
#define ALPHA 0.2f
#define CF 128   // HEADS*OUT_F
#define IN_F 128

// ---------------------------------------------------------------------------
// Kernel 1: Wh = h @ W   (N x 128 @ 128 x 128), fused with per-node
// attention scalars  s_src[n,h] = dot(Wh[n,h,:], a[h,0:32])
//                    s_dst[n,h] = dot(Wh[n,h,:], a[h,32:64])
// One wave per row; lane owns cols {2l, 2l+1}; W staged in LDS.
// ---------------------------------------------------------------------------
__global__ void k_gemm_wh(const float* __restrict__ h,
                          const float* __restrict__ W,
                          const float* __restrict__ a,
                          float* __restrict__ Wh,
                          float* __restrict__ ssrc,
                          float* __restrict__ sdst,
                          int N)
{
    __shared__ float Ws[IN_F * CF];      // 64 KB
    __shared__ float aS[CF], aD[CF];

    int tid = threadIdx.x;
    const float4* W4 = (const float4*)W;
    float4* Ws4 = (float4*)Ws;
    #pragma unroll
    for (int i = tid; i < (IN_F * CF) / 4; i += 256) Ws4[i] = W4[i];
    if (tid < CF) {
        int hh = tid >> 5, c = tid & 31;
        aS[tid] = a[hh * (2 * OUT_F + EDGE_F) + c];
        aD[tid] = a[hh * (2 * OUT_F + EDGE_F) + OUT_F + c];
    }
    __syncthreads();

    int wave = tid >> 6;
    int lane = tid & 63;
    int c0 = lane * 2;

    for (int r = blockIdx.x * 4 + wave; r < N; r += gridDim.x * 4) {
        const float* hr = h + (size_t)r * IN_F;
        float acc0 = 0.f, acc1 = 0.f;
        #pragma unroll 8
        for (int k = 0; k < IN_F; ++k) {
            float hv = hr[k];             // wave-uniform -> scalar load
            acc0 = fmaf(hv, Ws[k * CF + c0], acc0);
            acc1 = fmaf(hv, Ws[k * CF + c0 + 1], acc1);
        }
        *(float2*)(Wh + (size_t)r * CF + c0) = make_float2(acc0, acc1);

        float ps = acc0 * aS[c0] + acc1 * aS[c0 + 1];
        float pd = acc0 * aD[c0] + acc1 * aD[c0 + 1];
        #pragma unroll
        for (int off = 1; off < 16; off <<= 1) {
            ps += __shfl_xor(ps, off);
            pd += __shfl_xor(pd, off);
        }
        if ((lane & 15) == 0) {
            int hh = lane >> 4;
            ssrc[(size_t)r * HEADS + hh] = ps;
            sdst[(size_t)r * HEADS + hh] = pd;
        }
    }
}

// ---------------------------------------------------------------------------
// Kernel 2: per-edge attention + softmax over heads; also counts deg[src].
// ---------------------------------------------------------------------------
__global__ void k_att(const int* __restrict__ ei,
                      const float* __restrict__ ea,
                      const float* __restrict__ a,
                      const float* __restrict__ ssrc,
                      const float* __restrict__ sdst,
                      float* __restrict__ att,
                      int* __restrict__ deg,
                      int E)
{
    __shared__ float ae[HEADS][EDGE_F];
    int tid = threadIdx.x;
    if (tid < HEADS * EDGE_F) {
        int hh = tid >> 4, j = tid & 15;
        ae[hh][j] = a[hh * (2 * OUT_F + EDGE_F) + 2 * OUT_F + j];
    }
    __syncthreads();

    for (int e = blockIdx.x * blockDim.x + tid; e < E; e += gridDim.x * blockDim.x) {
        int s = ei[e];
        int d = ei[E + e];
        atomicAdd(&deg[s], 1);
        float4 es = *(const float4*)(ssrc + (size_t)s * HEADS);
        float4 ed = *(const float4*)(sdst + (size_t)d * HEADS);
        const float* eav = ea + (size_t)e * EDGE_F;
        float4 v0 = *(const float4*)(eav + 0);
        float4 v1 = *(const float4*)(eav + 4);
        float4 v2 = *(const float4*)(eav + 8);
        float4 v3 = *(const float4*)(eav + 12);

        float ev[HEADS];
        float base[HEADS] = {es.x + ed.x, es.y + ed.y, es.z + ed.z, es.w + ed.w};
        #pragma unroll
        for (int hh = 0; hh < HEADS; ++hh) {
            const float* av = ae[hh];
            float dotv = v0.x * av[0] + v0.y * av[1] + v0.z * av[2] + v0.w * av[3]
                       + v1.x * av[4] + v1.y * av[5] + v1.z * av[6] + v1.w * av[7]
                       + v2.x * av[8] + v2.y * av[9] + v2.z * av[10] + v2.w * av[11]
                       + v3.x * av[12] + v3.y * av[13] + v3.z * av[14] + v3.w * av[15];
            float x = base[hh] + dotv;
            ev[hh] = (x >= 0.f) ? x : ALPHA * x;
        }
        float m = fmaxf(fmaxf(ev[0], ev[1]), fmaxf(ev[2], ev[3]));
        float p0 = __expf(ev[0] - m), p1 = __expf(ev[1] - m);
        float p2 = __expf(ev[2] - m), p3 = __expf(ev[3] - m);
        float inv = 1.f / (p0 + p1 + p2 + p3);
        *(float4*)(att + (size_t)e * HEADS) =
            make_float4(p0 * inv, p1 * inv, p2 * inv, p3 * inv);
    }
}

// ---------------------------------------------------------------------------
// Kernel 3: single-block prefix sum  off[0..N] from deg[0..N-1].
// ---------------------------------------------------------------------------
__global__ void k_scan(const int* __restrict__ deg, int* __restrict__ off, int N)
{
    __shared__ int lds[1024];
    int tid = threadIdx.x;
    int per = (N + 1023) / 1024;
    int base = tid * per;
    int local = 0;
    for (int j = 0; j < per; ++j) {
        int idx = base + j;
        if (idx < N) local += deg[idx];
    }
    lds[tid] = local;
    __syncthreads();
    for (int st = 1; st < 1024; st <<= 1) {
        int v = lds[tid];
        int u = (tid >= st) ? lds[tid - st] : 0;
        __syncthreads();
        lds[tid] = v + u;
        __syncthreads();
    }
    int run = (tid == 0) ? 0 : lds[tid - 1];
    for (int j = 0; j < per; ++j) {
        int idx = base + j;
        if (idx < N) { off[idx] = run; run += deg[idx]; }
    }
    if (tid == 1023) off[N] = lds[1023];
}

// ---------------------------------------------------------------------------
// Kernel 4: bin edges by src:  elist2[off[s] + cursor[s]++] = (dst, e)
// ---------------------------------------------------------------------------
__global__ void k_fill(const int* __restrict__ ei,
                       const int* __restrict__ off,
                       int* __restrict__ cursor,
                       int2* __restrict__ elist2,
                       int E)
{
    int e = blockIdx.x * blockDim.x + threadIdx.x;
    if (e >= E) return;
    int s = ei[e];
    int d = ei[E + e];
    int pos = off[s] + atomicAdd(&cursor[s], 1);
    elist2[pos] = make_int2(d, e);
}

// ---------------------------------------------------------------------------
// Kernel 5: per-node register aggregation + fused ELU.
// One wave per node; lane owns channels {2l, 2l+1}; head = lane>>4.
// ---------------------------------------------------------------------------
__global__ void k_aggregate(const int* __restrict__ off,
                            const int2* __restrict__ elist2,
                            const float* __restrict__ att,
                            const float* __restrict__ Wh,
                            float* __restrict__ out,
                            int N)
{
    int wave = threadIdx.x >> 6;
    int lane = threadIdx.x & 63;
    int node = blockIdx.x * 4 + wave;
    if (node >= N) return;

    int beg = off[node];
    int end = off[node + 1];
    int c0 = lane * 2;
    int hh = lane >> 4;

    float acc0 = 0.f, acc1 = 0.f;
    for (int i = beg; i < end; ++i) {
        int2 ed = elist2[i];                         // (dst, e) — wave-uniform
        float w = att[(size_t)ed.y * HEADS + hh];    // 16-lane broadcast
        float2 wv = *(const float2*)(Wh + (size_t)ed.x * CF + c0);
        acc0 = fmaf(w, wv.x, acc0);
        acc1 = fmaf(w, wv.y, acc1);
    }
    acc0 = (acc0 > 0.f) ? acc0 : (__expf(acc0) - 1.f);
    acc1 = (acc1 > 0.f) ? acc1 : (__expf(acc1) - 1.f);
    *(float2*)(out + (size_t)node * CF + c0) = make_float2(acc0, acc1);
}

extern "C" void kernel_launch(void* const* d_in, const int* in_sizes, int n_in,
                              void* d_out, int out_size, void* d_ws, size_t ws_size,
                              hipStream_t stream)
{
    const float* h  = (const float*)d_in[0];
    const int*   ei = (const int*)d_in[1];
    const float* ea = (const float*)d_in[2];
    const float* W  = (const float*)d_in[3];
    const float* a  = (const float*)d_in[4];
    float* out = (float*)d_out;

    int N = in_sizes[0] / IN_F;     // 20000
    int E = in_sizes[1] / 2;        // 640000

    char* ws = (char*)d_ws;
    float* Wh     = (float*)ws;                 ws += (size_t)N * CF * sizeof(float);
    float* ssrc   = (float*)ws;                 ws += (size_t)N * HEADS * sizeof(float);
    float* sdst   = (float*)ws;                 ws += (size_t)N * HEADS * sizeof(float);
    float* att    = (float*)ws;                 ws += (size_t)E * HEADS * sizeof(float);
    int2*  elist2 = (int2*)ws;                  ws += (size_t)E * sizeof(int2);
    int*   deg    = (int*)ws;                   ws += (size_t)N * sizeof(int);
    int*   cursor = (int*)ws;                   ws += (size_t)N * sizeof(int);
    int*   off    = (int*)ws;                   ws += (size_t)(N + 1) * sizeof(int);

    // zero deg + cursor (adjacent) in one call
    hipMemsetAsync(deg, 0, 2 * (size_t)N * sizeof(int), stream);

    k_gemm_wh<<<1024, 256, 0, stream>>>(h, W, a, Wh, ssrc, sdst, N);
    k_att<<<(E + 255) / 256, 256, 0, stream>>>(ei, ea, a, ssrc, sdst, att, deg, E);
    k_scan<<<1, 1024, 0, stream>>>(deg, off, N);
    k_fill<<<(E + 255) / 256, 256, 0, stream>>>(ei, off, cursor, elist2, E);
    k_aggregate<<<(N + 3) / 4, 256, 0, stream>>>(off, elist2, att, Wh, out, N);
}

// Round 3
// 175.877 us; speedup vs baseline: 6.4866x; 1.2670x over previous
//
#include <hip/hip_runtime.h>
#include <math.h>

#define HEADS 4
#define OUT_F 32
#define EDGE_F 16
#define ALPHA 0.2f
#define CF 128      // HEADS*OUT_F
#define IN_F 128
#define BM 64       // rows per gemm block
#define AROW (2*OUT_F+EDGE_F)   // 80

typedef __attribute__((ext_vector_type(4))) unsigned short us4;

static __device__ __forceinline__ unsigned short f2b(float x) {
    union { float f; unsigned u; } v; v.f = x;
    unsigned r = v.u + 0x7FFFu + ((v.u >> 16) & 1u);   // round-to-nearest-even
    return (unsigned short)(r >> 16);
}
static __device__ __forceinline__ float b2f(unsigned short u) {
    union { unsigned u32; float f; } v; v.u32 = ((unsigned)u) << 16;
    return v.f;
}

// ---------------------------------------------------------------------------
// Kernel 1: Wh = h @ W  (register-tiled, bf16 LDS operands, bf16 Wh output)
// fused per-node scalars ssrc/sdst. Block: 64 rows x 128 cols, 256 threads,
// thread tile = 8 rows x 4 cols.
// ---------------------------------------------------------------------------
__global__ __launch_bounds__(256) void k_gemm(const float* __restrict__ h,
                                              const float* __restrict__ W,
                                              const float* __restrict__ a,
                                              unsigned short* __restrict__ Whb,
                                              float* __restrict__ ssrc,
                                              float* __restrict__ sdst,
                                              int N)
{
    __shared__ unsigned short Wsb[IN_F * CF];   // [k][c]  32 KB
    __shared__ unsigned short Hsb[IN_F * BM];   // [k][r]  16 KB
    __shared__ float aS[CF], aD[CF];

    int tid = threadIdx.x;
    int r0 = blockIdx.x * BM;

    // stage W -> bf16 LDS (16384 elems)
    for (int i = tid * 4; i < IN_F * CF; i += 1024) {
        float4 w = *(const float4*)(W + i);
        us4 u = { f2b(w.x), f2b(w.y), f2b(w.z), f2b(w.w) };
        *(us4*)(Wsb + i) = u;
    }
    if (tid < CF) {
        int g = tid >> 5, c = tid & 31;
        aS[tid] = a[g * AROW + c];
        aD[tid] = a[g * AROW + OUT_F + c];
    }
    // stage h rows r0..r0+63 transposed -> Hsb[k][r]
    for (int i4 = tid; i4 < (IN_F * BM) / 4; i4 += 256) {
        int r = i4 & (BM - 1);
        int k = (i4 >> 6) * 4;
        int row = r0 + r;
        float4 v = make_float4(0.f, 0.f, 0.f, 0.f);
        if (row < N) v = *(const float4*)(h + (size_t)row * IN_F + k);
        Hsb[(k + 0) * BM + r] = f2b(v.x);
        Hsb[(k + 1) * BM + r] = f2b(v.y);
        Hsb[(k + 2) * BM + r] = f2b(v.z);
        Hsb[(k + 3) * BM + r] = f2b(v.w);
    }
    __syncthreads();

    int tc = tid & 31;   // col group: cols 4tc..4tc+3
    int tr = tid >> 5;   // row group: rows 8tr..8tr+7

    float acc[8][4];
    #pragma unroll
    for (int r = 0; r < 8; ++r)
        #pragma unroll
        for (int j = 0; j < 4; ++j) acc[r][j] = 0.f;

    #pragma unroll 4
    for (int k = 0; k < IN_F; ++k) {
        us4 wu = *(const us4*)(Wsb + k * CF + tc * 4);
        float w0 = b2f(wu.x), w1 = b2f(wu.y), w2 = b2f(wu.z), w3 = b2f(wu.w);
        us4 hu0 = *(const us4*)(Hsb + k * BM + tr * 8);
        us4 hu1 = *(const us4*)(Hsb + k * BM + tr * 8 + 4);
        float hr[8] = { b2f(hu0.x), b2f(hu0.y), b2f(hu0.z), b2f(hu0.w),
                        b2f(hu1.x), b2f(hu1.y), b2f(hu1.z), b2f(hu1.w) };
        #pragma unroll
        for (int r = 0; r < 8; ++r) {
            acc[r][0] = fmaf(hr[r], w0, acc[r][0]);
            acc[r][1] = fmaf(hr[r], w1, acc[r][1]);
            acc[r][2] = fmaf(hr[r], w2, acc[r][2]);
            acc[r][3] = fmaf(hr[r], w3, acc[r][3]);
        }
    }

    // write Wh (bf16)
    #pragma unroll
    for (int r = 0; r < 8; ++r) {
        int row = r0 + tr * 8 + r;
        if (row < N) {
            us4 u = { f2b(acc[r][0]), f2b(acc[r][1]), f2b(acc[r][2]), f2b(acc[r][3]) };
            *(us4*)(Whb + (size_t)row * CF + tc * 4) = u;
        }
    }

    // fused ssrc/sdst: per-row per-head dot, reduce across the 8 col-threads
    // of each head (lane bits 0..2).
    int g = tc >> 3;
    int lane = tid & 63;
    #pragma unroll
    for (int r = 0; r < 8; ++r) {
        float ps = acc[r][0] * aS[tc*4] + acc[r][1] * aS[tc*4+1]
                 + acc[r][2] * aS[tc*4+2] + acc[r][3] * aS[tc*4+3];
        float pd = acc[r][0] * aD[tc*4] + acc[r][1] * aD[tc*4+1]
                 + acc[r][2] * aD[tc*4+2] + acc[r][3] * aD[tc*4+3];
        #pragma unroll
        for (int off = 1; off < 8; off <<= 1) {
            ps += __shfl_xor(ps, off);
            pd += __shfl_xor(pd, off);
        }
        if ((lane & 7) == 0) {
            int row = r0 + tr * 8 + r;
            if (row < N) {
                ssrc[(size_t)row * HEADS + g] = ps;
                sdst[(size_t)row * HEADS + g] = pd;
            }
        }
    }
}

// ---------------------------------------------------------------------------
// Kernel 2: deg[src]++
// ---------------------------------------------------------------------------
__global__ void k_count(const int* __restrict__ ei, int* __restrict__ deg, int E)
{
    int e = blockIdx.x * blockDim.x + threadIdx.x;
    if (e < E) atomicAdd(&deg[ei[e]], 1);
}

// ---------------------------------------------------------------------------
// Kernel 3: single-block shfl-based exclusive scan, off[0..N].
// ---------------------------------------------------------------------------
__global__ __launch_bounds__(1024) void k_scan(const int* __restrict__ deg,
                                               int* __restrict__ off, int N)
{
    __shared__ int wsum[16], wpre[17];
    int tid = threadIdx.x;
    int lane = tid & 63, wid = tid >> 6;
    int per = (N + 1023) / 1024;
    int base = tid * per;

    int local = 0;
    for (int j = 0; j < per; ++j) {
        int idx = base + j;
        if (idx < N) local += deg[idx];
    }
    int v = local;
    #pragma unroll
    for (int o = 1; o < 64; o <<= 1) {
        int u = __shfl_up(v, o);
        if (lane >= o) v += u;
    }
    if (lane == 63) wsum[wid] = v;
    __syncthreads();
    if (tid == 0) {
        int run = 0;
        for (int w = 0; w < 16; ++w) { wpre[w] = run; run += wsum[w]; }
        wpre[16] = run;
    }
    __syncthreads();
    int run = wpre[wid] + v - local;   // exclusive prefix of this thread
    for (int j = 0; j < per; ++j) {
        int idx = base + j;
        if (idx < N) { off[idx] = run; run += deg[idx]; }
    }
    if (tid == 0) off[N] = wpre[16];
}

// ---------------------------------------------------------------------------
// Kernel 4: fused attention + bin-by-src. Writes dst and attention weights
// directly at the sorted position, so aggregate reads them streaming.
// ---------------------------------------------------------------------------
__global__ void k_att_fill(const int* __restrict__ ei,
                           const float* __restrict__ ea,
                           const float* __restrict__ a,
                           const float* __restrict__ ssrc,
                           const float* __restrict__ sdst,
                           const int* __restrict__ off,
                           int* __restrict__ cursor,
                           int* __restrict__ elist_dst,
                           float* __restrict__ att4,
                           int E)
{
    __shared__ float ae[HEADS][EDGE_F];
    int tid = threadIdx.x;
    if (tid < HEADS * EDGE_F) {
        int g = tid >> 4, j = tid & 15;
        ae[g][j] = a[g * AROW + 2 * OUT_F + j];
    }
    __syncthreads();

    int e = blockIdx.x * blockDim.x + tid;
    if (e >= E) return;

    int s = ei[e];
    int d = ei[E + e];
    float4 es = *(const float4*)(ssrc + (size_t)s * HEADS);
    float4 ed = *(const float4*)(sdst + (size_t)d * HEADS);
    const float* eav = ea + (size_t)e * EDGE_F;
    float4 v0 = *(const float4*)(eav + 0);
    float4 v1 = *(const float4*)(eav + 4);
    float4 v2 = *(const float4*)(eav + 8);
    float4 v3 = *(const float4*)(eav + 12);

    float ev[HEADS];
    float base[HEADS] = { es.x + ed.x, es.y + ed.y, es.z + ed.z, es.w + ed.w };
    #pragma unroll
    for (int g = 0; g < HEADS; ++g) {
        const float* av = ae[g];
        float dotv = v0.x*av[0] + v0.y*av[1] + v0.z*av[2] + v0.w*av[3]
                   + v1.x*av[4] + v1.y*av[5] + v1.z*av[6] + v1.w*av[7]
                   + v2.x*av[8] + v2.y*av[9] + v2.z*av[10] + v2.w*av[11]
                   + v3.x*av[12] + v3.y*av[13] + v3.z*av[14] + v3.w*av[15];
        float x = base[g] + dotv;
        ev[g] = (x >= 0.f) ? x : ALPHA * x;
    }
    float m = fmaxf(fmaxf(ev[0], ev[1]), fmaxf(ev[2], ev[3]));
    float p0 = __expf(ev[0] - m), p1 = __expf(ev[1] - m);
    float p2 = __expf(ev[2] - m), p3 = __expf(ev[3] - m);
    float inv = 1.f / (p0 + p1 + p2 + p3);

    int pos = off[s] + atomicAdd(&cursor[s], 1);
    elist_dst[pos] = d;
    *(float4*)(att4 + (size_t)pos * HEADS) =
        make_float4(p0 * inv, p1 * inv, p2 * inv, p3 * inv);
}

// ---------------------------------------------------------------------------
// Kernel 5: per-node register aggregation + fused ELU.
// One wave per node; lane owns channels {2l,2l+1}; head = lane>>4.
// elist/att reads are streaming; Wh gathers are bf16 (256 B/edge).
// ---------------------------------------------------------------------------
__global__ __launch_bounds__(256) void k_aggregate(const int* __restrict__ off,
                                                   const int* __restrict__ elist_dst,
                                                   const float* __restrict__ att4,
                                                   const unsigned short* __restrict__ Whb,
                                                   float* __restrict__ out,
                                                   int N)
{
    int wave = threadIdx.x >> 6;
    int lane = threadIdx.x & 63;
    int node = blockIdx.x * 4 + wave;
    if (node >= N) return;

    int beg = off[node];
    int end = off[node + 1];
    int c0 = lane * 2;
    int hh = lane >> 4;

    float acc0 = 0.f, acc1 = 0.f;
    int i = beg;
    for (; i + 1 < end; i += 2) {
        int d0 = elist_dst[i];
        int d1 = elist_dst[i + 1];
        float w0 = att4[(size_t)i * HEADS + hh];
        float w1 = att4[(size_t)(i + 1) * HEADS + hh];
        ushort2 a0 = *(const ushort2*)(Whb + (size_t)d0 * CF + c0);
        ushort2 a1 = *(const ushort2*)(Whb + (size_t)d1 * CF + c0);
        acc0 = fmaf(w0, b2f(a0.x), acc0);
        acc1 = fmaf(w0, b2f(a0.y), acc1);
        acc0 = fmaf(w1, b2f(a1.x), acc0);
        acc1 = fmaf(w1, b2f(a1.y), acc1);
    }
    if (i < end) {
        int d0 = elist_dst[i];
        float w0 = att4[(size_t)i * HEADS + hh];
        ushort2 a0 = *(const ushort2*)(Whb + (size_t)d0 * CF + c0);
        acc0 = fmaf(w0, b2f(a0.x), acc0);
        acc1 = fmaf(w0, b2f(a0.y), acc1);
    }
    acc0 = (acc0 > 0.f) ? acc0 : (__expf(acc0) - 1.f);
    acc1 = (acc1 > 0.f) ? acc1 : (__expf(acc1) - 1.f);
    *(float2*)(out + (size_t)node * CF + c0) = make_float2(acc0, acc1);
}

extern "C" void kernel_launch(void* const* d_in, const int* in_sizes, int n_in,
                              void* d_out, int out_size, void* d_ws, size_t ws_size,
                              hipStream_t stream)
{
    const float* h  = (const float*)d_in[0];
    const int*   ei = (const int*)d_in[1];
    const float* ea = (const float*)d_in[2];
    const float* W  = (const float*)d_in[3];
    const float* a  = (const float*)d_in[4];
    float* out = (float*)d_out;

    int N = in_sizes[0] / IN_F;     // 20000
    int E = in_sizes[1] / 2;        // 640000

    char* ws = (char*)d_ws;
    float*          att4      = (float*)ws;          ws += (size_t)E * HEADS * sizeof(float);
    unsigned short* Whb       = (unsigned short*)ws; ws += (size_t)N * CF * sizeof(unsigned short);
    float*          ssrc      = (float*)ws;          ws += (size_t)N * HEADS * sizeof(float);
    float*          sdst      = (float*)ws;          ws += (size_t)N * HEADS * sizeof(float);
    int*            elist_dst = (int*)ws;            ws += (size_t)E * sizeof(int);
    int*            deg       = (int*)ws;            ws += (size_t)N * sizeof(int);
    int*            cursor    = (int*)ws;            ws += (size_t)N * sizeof(int);
    int*            off       = (int*)ws;            ws += (size_t)(N + 1) * sizeof(int);

    // zero deg + cursor (adjacent) in one call
    hipMemsetAsync(deg, 0, 2 * (size_t)N * sizeof(int), stream);

    k_gemm<<<(N + BM - 1) / BM, 256, 0, stream>>>(h, W, a, Whb, ssrc, sdst, N);
    k_count<<<(E + 255) / 256, 256, 0, stream>>>(ei, deg, E);
    k_scan<<<1, 1024, 0, stream>>>(deg, off, N);
    k_att_fill<<<(E + 255) / 256, 256, 0, stream>>>(ei, ea, a, ssrc, sdst, off,
                                                    cursor, elist_dst, att4, E);
    k_aggregate<<<(N + 3) / 4, 256, 0, stream>>>(off, elist_dst, att4, Whb, out, N);
}

// Round 4
// 167.264 us; speedup vs baseline: 6.8206x; 1.0515x over previous
//
#include <hip/hip_runtime.h>
#include <math.h>

#define HEADS 4
#define OUT_F 32
#define EDGE_F 16
#define ALPHA 0.2f
#define CF 128      // HEADS*OUT_F
#define IN_F 128
#define BM 32       // rows per gemm block
#define AROW (2*OUT_F+EDGE_F)   // 80

typedef __attribute__((ext_vector_type(4))) unsigned short us4;

static __device__ __forceinline__ unsigned short f2b(float x) {
    union { float f; unsigned u; } v; v.f = x;
    unsigned r = v.u + 0x7FFFu + ((v.u >> 16) & 1u);   // round-to-nearest-even
    return (unsigned short)(r >> 16);
}
static __device__ __forceinline__ float b2f(unsigned short u) {
    union { unsigned u32; float f; } v; v.u32 = ((unsigned)u) << 16;
    return v.f;
}

// ---------------------------------------------------------------------------
// Kernel 1: Wh = h @ W  (register-tiled, bf16 LDS operands, bf16 Wh output)
// fused per-node scalars ssrc/sdst. Block: 32 rows x 128 cols, 256 threads,
// thread tile = 4 rows x 4 cols. 625 blocks for N=20000.
// ---------------------------------------------------------------------------
__global__ __launch_bounds__(256) void k_gemm(const float* __restrict__ h,
                                              const float* __restrict__ W,
                                              const float* __restrict__ a,
                                              unsigned short* __restrict__ Whb,
                                              float* __restrict__ ssrc,
                                              float* __restrict__ sdst,
                                              int N)
{
    __shared__ unsigned short Wsb[IN_F * CF];   // [k][c]  32 KB
    __shared__ unsigned short Hsb[IN_F * BM];   // [k][r]   8 KB
    __shared__ float aS[CF], aD[CF];

    int tid = threadIdx.x;
    int r0 = blockIdx.x * BM;

    // stage W -> bf16 LDS (16384 elems, coalesced float4)
    for (int i = tid * 4; i < IN_F * CF; i += 1024) {
        float4 w = *(const float4*)(W + i);
        us4 u = { f2b(w.x), f2b(w.y), f2b(w.z), f2b(w.w) };
        *(us4*)(Wsb + i) = u;
    }
    if (tid < CF) {
        int g = tid >> 5, c = tid & 31;
        aS[tid] = a[g * AROW + c];
        aD[tid] = a[g * AROW + OUT_F + c];
    }
    // stage h rows r0..r0+31 transposed -> Hsb[k][r]
    for (int i4 = tid; i4 < (IN_F * BM) / 4; i4 += 256) {
        int r = i4 & (BM - 1);
        int k = (i4 >> 5) * 4;
        int row = r0 + r;
        float4 v = make_float4(0.f, 0.f, 0.f, 0.f);
        if (row < N) v = *(const float4*)(h + (size_t)row * IN_F + k);
        Hsb[(k + 0) * BM + r] = f2b(v.x);
        Hsb[(k + 1) * BM + r] = f2b(v.y);
        Hsb[(k + 2) * BM + r] = f2b(v.z);
        Hsb[(k + 3) * BM + r] = f2b(v.w);
    }
    __syncthreads();

    int tc = tid & 31;   // col group: cols 4tc..4tc+3
    int tr = tid >> 5;   // row group: rows 4tr..4tr+3

    float acc[4][4];
    #pragma unroll
    for (int r = 0; r < 4; ++r)
        #pragma unroll
        for (int j = 0; j < 4; ++j) acc[r][j] = 0.f;

    #pragma unroll 4
    for (int k = 0; k < IN_F; ++k) {
        us4 wu = *(const us4*)(Wsb + k * CF + tc * 4);
        us4 hu = *(const us4*)(Hsb + k * BM + tr * 4);
        float w0 = b2f(wu.x), w1 = b2f(wu.y), w2 = b2f(wu.z), w3 = b2f(wu.w);
        float hr[4] = { b2f(hu.x), b2f(hu.y), b2f(hu.z), b2f(hu.w) };
        #pragma unroll
        for (int r = 0; r < 4; ++r) {
            acc[r][0] = fmaf(hr[r], w0, acc[r][0]);
            acc[r][1] = fmaf(hr[r], w1, acc[r][1]);
            acc[r][2] = fmaf(hr[r], w2, acc[r][2]);
            acc[r][3] = fmaf(hr[r], w3, acc[r][3]);
        }
    }

    // write Wh (bf16)
    #pragma unroll
    for (int r = 0; r < 4; ++r) {
        int row = r0 + tr * 4 + r;
        if (row < N) {
            us4 u = { f2b(acc[r][0]), f2b(acc[r][1]), f2b(acc[r][2]), f2b(acc[r][3]) };
            *(us4*)(Whb + (size_t)row * CF + tc * 4) = u;
        }
    }

    // fused ssrc/sdst: per-row per-head dot, reduce across 8 col-threads/head
    int g = tc >> 3;
    int lane = tid & 63;
    #pragma unroll
    for (int r = 0; r < 4; ++r) {
        float ps = acc[r][0] * aS[tc*4] + acc[r][1] * aS[tc*4+1]
                 + acc[r][2] * aS[tc*4+2] + acc[r][3] * aS[tc*4+3];
        float pd = acc[r][0] * aD[tc*4] + acc[r][1] * aD[tc*4+1]
                 + acc[r][2] * aD[tc*4+2] + acc[r][3] * aD[tc*4+3];
        #pragma unroll
        for (int off = 1; off < 8; off <<= 1) {
            ps += __shfl_xor(ps, off);
            pd += __shfl_xor(pd, off);
        }
        if ((lane & 7) == 0) {
            int row = r0 + tr * 4 + r;
            if (row < N) {
                ssrc[(size_t)row * HEADS + g] = ps;
                sdst[(size_t)row * HEADS + g] = pd;
            }
        }
    }
}

// ---------------------------------------------------------------------------
// Kernel 2: deg[src]++ (4 edges per thread, int4 loads)
// ---------------------------------------------------------------------------
__global__ void k_count(const int* __restrict__ ei, int* __restrict__ deg, int E)
{
    int i = blockIdx.x * blockDim.x + threadIdx.x;
    int e0 = i * 4;
    if (e0 >= E) return;
    if (e0 + 3 < E) {
        int4 s = *(const int4*)(ei + e0);
        atomicAdd(&deg[s.x], 1);
        atomicAdd(&deg[s.y], 1);
        atomicAdd(&deg[s.z], 1);
        atomicAdd(&deg[s.w], 1);
    } else {
        for (int e = e0; e < E; ++e) atomicAdd(&deg[ei[e]], 1);
    }
}

// ---------------------------------------------------------------------------
// Kernel 3: single-block shfl-based exclusive scan; writes off[] AND cursor[].
// ---------------------------------------------------------------------------
__global__ __launch_bounds__(1024) void k_scan(const int* __restrict__ deg,
                                               int* __restrict__ off,
                                               int* __restrict__ cursor, int N)
{
    __shared__ int wsum[16], wpre[17];
    int tid = threadIdx.x;
    int lane = tid & 63, wid = tid >> 6;
    int per = (N + 1023) / 1024;
    int base = tid * per;

    int local = 0;
    for (int j = 0; j < per; ++j) {
        int idx = base + j;
        if (idx < N) local += deg[idx];
    }
    int v = local;
    #pragma unroll
    for (int o = 1; o < 64; o <<= 1) {
        int u = __shfl_up(v, o);
        if (lane >= o) v += u;
    }
    if (lane == 63) wsum[wid] = v;
    __syncthreads();
    if (tid == 0) {
        int run = 0;
        for (int w = 0; w < 16; ++w) { wpre[w] = run; run += wsum[w]; }
        wpre[16] = run;
    }
    __syncthreads();
    int run = wpre[wid] + v - local;   // exclusive prefix of this thread
    for (int j = 0; j < per; ++j) {
        int idx = base + j;
        if (idx < N) { off[idx] = run; cursor[idx] = run; run += deg[idx]; }
    }
    if (tid == 0) off[N] = wpre[16];
}

// ---------------------------------------------------------------------------
// Kernel 4: fused attention + bin-by-src. One 16 B record per edge:
// { dst, bf16(att0)|bf16(att1)<<16, bf16(att2)|bf16(att3)<<16, 0 }.
// Two edges per thread for MLP depth.
// ---------------------------------------------------------------------------
static __device__ __forceinline__ void att_one(int s, int d, int e,
                                               const float* __restrict__ ea,
                                               const float (*ae)[EDGE_F],
                                               const float* __restrict__ ssrc,
                                               const float* __restrict__ sdst,
                                               int* __restrict__ cursor,
                                               int4* __restrict__ recs)
{
    float4 es = *(const float4*)(ssrc + (size_t)s * HEADS);
    float4 ed = *(const float4*)(sdst + (size_t)d * HEADS);
    const float* eav = ea + (size_t)e * EDGE_F;
    float4 v0 = *(const float4*)(eav + 0);
    float4 v1 = *(const float4*)(eav + 4);
    float4 v2 = *(const float4*)(eav + 8);
    float4 v3 = *(const float4*)(eav + 12);

    float ev[HEADS];
    float base[HEADS] = { es.x + ed.x, es.y + ed.y, es.z + ed.z, es.w + ed.w };
    #pragma unroll
    for (int g = 0; g < HEADS; ++g) {
        const float* av = ae[g];
        float dotv = v0.x*av[0] + v0.y*av[1] + v0.z*av[2] + v0.w*av[3]
                   + v1.x*av[4] + v1.y*av[5] + v1.z*av[6] + v1.w*av[7]
                   + v2.x*av[8] + v2.y*av[9] + v2.z*av[10] + v2.w*av[11]
                   + v3.x*av[12] + v3.y*av[13] + v3.z*av[14] + v3.w*av[15];
        float x = base[g] + dotv;
        ev[g] = (x >= 0.f) ? x : ALPHA * x;
    }
    float m = fmaxf(fmaxf(ev[0], ev[1]), fmaxf(ev[2], ev[3]));
    float p0 = __expf(ev[0] - m), p1 = __expf(ev[1] - m);
    float p2 = __expf(ev[2] - m), p3 = __expf(ev[3] - m);
    float inv = 1.f / (p0 + p1 + p2 + p3);

    unsigned a01 = (unsigned)f2b(p0 * inv) | ((unsigned)f2b(p1 * inv) << 16);
    unsigned a23 = (unsigned)f2b(p2 * inv) | ((unsigned)f2b(p3 * inv) << 16);

    int pos = atomicAdd(&cursor[s], 1);
    recs[pos] = make_int4(d, (int)a01, (int)a23, 0);
}

__global__ __launch_bounds__(256) void k_att_fill(const int* __restrict__ ei,
                                                  const float* __restrict__ ea,
                                                  const float* __restrict__ a,
                                                  const float* __restrict__ ssrc,
                                                  const float* __restrict__ sdst,
                                                  int* __restrict__ cursor,
                                                  int4* __restrict__ recs,
                                                  int E)
{
    __shared__ float ae[HEADS][EDGE_F];
    int tid = threadIdx.x;
    if (tid < HEADS * EDGE_F) {
        int g = tid >> 4, j = tid & 15;
        ae[g][j] = a[g * AROW + 2 * OUT_F + j];
    }
    __syncthreads();

    int E2 = (E + 1) >> 1;
    int t = blockIdx.x * blockDim.x + tid;
    if (t >= E2) return;
    int eA = t, eB = t + E2;

    int sA = ei[eA], dA = ei[E + eA];
    if (eB < E) {
        int sB = ei[eB], dB = ei[E + eB];
        att_one(sA, dA, eA, ea, ae, ssrc, sdst, cursor, recs);
        att_one(sB, dB, eB, ea, ae, ssrc, sdst, cursor, recs);
    } else {
        att_one(sA, dA, eA, ea, ae, ssrc, sdst, cursor, recs);
    }
}

// ---------------------------------------------------------------------------
// Kernel 5: per-node register aggregation + fused ELU.
// One wave per node; lane owns channels {2l,2l+1}; head = lane>>4.
// 4-edge unroll: 4 record broadcasts + 4 bf16 row gathers per round trip.
// ---------------------------------------------------------------------------
static __device__ __forceinline__ float att_of(int4 r, int hh) {
    unsigned w = (hh & 2) ? (unsigned)r.z : (unsigned)r.y;
    unsigned short u = (hh & 1) ? (unsigned short)(w >> 16) : (unsigned short)(w & 0xffffu);
    return b2f(u);
}

__global__ __launch_bounds__(256) void k_aggregate(const int* __restrict__ off,
                                                   const int4* __restrict__ recs,
                                                   const unsigned short* __restrict__ Whb,
                                                   float* __restrict__ out,
                                                   int N)
{
    int wave = threadIdx.x >> 6;
    int lane = threadIdx.x & 63;
    int node = blockIdx.x * 4 + wave;
    if (node >= N) return;

    int beg = off[node];
    int end = off[node + 1];
    int c0 = lane * 2;
    int hh = lane >> 4;

    float acc0 = 0.f, acc1 = 0.f;
    int i = beg;
    for (; i + 3 < end; i += 4) {
        int4 r0 = recs[i];
        int4 r1 = recs[i + 1];
        int4 r2 = recs[i + 2];
        int4 r3 = recs[i + 3];
        ushort2 w0 = *(const ushort2*)(Whb + (size_t)r0.x * CF + c0);
        ushort2 w1 = *(const ushort2*)(Whb + (size_t)r1.x * CF + c0);
        ushort2 w2 = *(const ushort2*)(Whb + (size_t)r2.x * CF + c0);
        ushort2 w3 = *(const ushort2*)(Whb + (size_t)r3.x * CF + c0);
        float a0 = att_of(r0, hh), a1 = att_of(r1, hh);
        float a2 = att_of(r2, hh), a3 = att_of(r3, hh);
        acc0 = fmaf(a0, b2f(w0.x), acc0); acc1 = fmaf(a0, b2f(w0.y), acc1);
        acc0 = fmaf(a1, b2f(w1.x), acc0); acc1 = fmaf(a1, b2f(w1.y), acc1);
        acc0 = fmaf(a2, b2f(w2.x), acc0); acc1 = fmaf(a2, b2f(w2.y), acc1);
        acc0 = fmaf(a3, b2f(w3.x), acc0); acc1 = fmaf(a3, b2f(w3.y), acc1);
    }
    for (; i < end; ++i) {
        int4 r0 = recs[i];
        ushort2 w0 = *(const ushort2*)(Whb + (size_t)r0.x * CF + c0);
        float a0 = att_of(r0, hh);
        acc0 = fmaf(a0, b2f(w0.x), acc0); acc1 = fmaf(a0, b2f(w0.y), acc1);
    }
    acc0 = (acc0 > 0.f) ? acc0 : (__expf(acc0) - 1.f);
    acc1 = (acc1 > 0.f) ? acc1 : (__expf(acc1) - 1.f);
    *(float2*)(out + (size_t)node * CF + c0) = make_float2(acc0, acc1);
}

extern "C" void kernel_launch(void* const* d_in, const int* in_sizes, int n_in,
                              void* d_out, int out_size, void* d_ws, size_t ws_size,
                              hipStream_t stream)
{
    const float* h  = (const float*)d_in[0];
    const int*   ei = (const int*)d_in[1];
    const float* ea = (const float*)d_in[2];
    const float* W  = (const float*)d_in[3];
    const float* a  = (const float*)d_in[4];
    float* out = (float*)d_out;

    int N = in_sizes[0] / IN_F;     // 20000
    int E = in_sizes[1] / 2;        // 640000

    char* ws = (char*)d_ws;
    int4*           recs   = (int4*)ws;           ws += (size_t)E * sizeof(int4);
    unsigned short* Whb    = (unsigned short*)ws; ws += (size_t)N * CF * sizeof(unsigned short);
    float*          ssrc   = (float*)ws;          ws += (size_t)N * HEADS * sizeof(float);
    float*          sdst   = (float*)ws;          ws += (size_t)N * HEADS * sizeof(float);
    int*            deg    = (int*)ws;            ws += (size_t)N * sizeof(int);
    int*            cursor = (int*)ws;            ws += (size_t)N * sizeof(int);
    int*            off    = (int*)ws;            ws += (size_t)(N + 1) * sizeof(int);

    hipMemsetAsync(deg, 0, (size_t)N * sizeof(int), stream);

    k_gemm<<<(N + BM - 1) / BM, 256, 0, stream>>>(h, W, a, Whb, ssrc, sdst, N);
    k_count<<<(E + 1023) / 1024, 256, 0, stream>>>(ei, deg, E);
    k_scan<<<1, 1024, 0, stream>>>(deg, off, cursor, N);
    int E2 = (E + 1) >> 1;
    k_att_fill<<<(E2 + 255) / 256, 256, 0, stream>>>(ei, ea, a, ssrc, sdst,
                                                     cursor, recs, E);
    k_aggregate<<<(N + 3) / 4, 256, 0, stream>>>(off, recs, Whb, out, N);
}

// Round 5
// 148.575 us; speedup vs baseline: 7.6786x; 1.1258x over previous
//
#include <hip/hip_runtime.h>
#include <math.h>

#define HEADS 4
#define OUT_F 32
#define EDGE_F 16
#define ALPHA 0.2f
#define CF 128      // HEADS*OUT_F
#define IN_F 128
#define BM 32       // rows per gemm block
#define AROW (2*OUT_F+EDGE_F)   // 80

typedef __attribute__((ext_vector_type(4))) unsigned short us4;
typedef unsigned long long u64;

static __device__ __forceinline__ unsigned short f2b(float x) {
    union { float f; unsigned u; } v; v.f = x;
    unsigned r = v.u + 0x7FFFu + ((v.u >> 16) & 1u);   // round-to-nearest-even
    return (unsigned short)(r >> 16);
}
static __device__ __forceinline__ float b2f(unsigned short u) {
    union { unsigned u32; float f; } v; v.u32 = ((unsigned)u) << 16;
    return v.f;
}

// ---------------------------------------------------------------------------
// Kernel A (fused): blocks [0, GB) do the GEMM Wh = h@W (+ ssrc/sdst);
// blocks [GB, GB+CB) do deg[src]++ and edot[e] = ea[e] . a_edge[h].
// The latency-bound edge blocks overlap the compute-bound GEMM blocks.
// ---------------------------------------------------------------------------
__global__ __launch_bounds__(256) void k_fused(const float* __restrict__ h,
                                               const float* __restrict__ W,
                                               const float* __restrict__ a,
                                               const int* __restrict__ ei,
                                               const float* __restrict__ ea,
                                               unsigned short* __restrict__ Whb,
                                               float* __restrict__ ssrc,
                                               float* __restrict__ sdst,
                                               float4* __restrict__ edot4,
                                               int* __restrict__ deg,
                                               int N, int E, int GB)
{
    __shared__ char smem[(IN_F*CF + IN_F*BM) * 2 + 2 * CF * 4];  // 41984 B
    int tid = threadIdx.x;
    int b = blockIdx.x;

    if (b < GB) {
        // ----- GEMM path -----
        unsigned short* Wsb = (unsigned short*)smem;          // [k][c] 32 KB
        unsigned short* Hsb = Wsb + IN_F * CF;                // [k][r]  8 KB
        float* aS = (float*)(Hsb + IN_F * BM);
        float* aD = aS + CF;
        int r0 = b * BM;

        for (int i = tid * 4; i < IN_F * CF; i += 1024) {
            float4 w = *(const float4*)(W + i);
            us4 u = { f2b(w.x), f2b(w.y), f2b(w.z), f2b(w.w) };
            *(us4*)(Wsb + i) = u;
        }
        if (tid < CF) {
            int g = tid >> 5, c = tid & 31;
            aS[tid] = a[g * AROW + c];
            aD[tid] = a[g * AROW + OUT_F + c];
        }
        for (int i4 = tid; i4 < (IN_F * BM) / 4; i4 += 256) {
            int r = i4 & (BM - 1);
            int k = (i4 >> 5) * 4;
            int row = r0 + r;
            float4 v = make_float4(0.f, 0.f, 0.f, 0.f);
            if (row < N) v = *(const float4*)(h + (size_t)row * IN_F + k);
            Hsb[(k + 0) * BM + r] = f2b(v.x);
            Hsb[(k + 1) * BM + r] = f2b(v.y);
            Hsb[(k + 2) * BM + r] = f2b(v.z);
            Hsb[(k + 3) * BM + r] = f2b(v.w);
        }
        __syncthreads();

        int tc = tid & 31;   // cols 4tc..4tc+3
        int tr = tid >> 5;   // rows 4tr..4tr+3

        float acc[4][4];
        #pragma unroll
        for (int r = 0; r < 4; ++r)
            #pragma unroll
            for (int j = 0; j < 4; ++j) acc[r][j] = 0.f;

        #pragma unroll 4
        for (int k = 0; k < IN_F; ++k) {
            us4 wu = *(const us4*)(Wsb + k * CF + tc * 4);
            us4 hu = *(const us4*)(Hsb + k * BM + tr * 4);
            float w0 = b2f(wu.x), w1 = b2f(wu.y), w2 = b2f(wu.z), w3 = b2f(wu.w);
            float hr[4] = { b2f(hu.x), b2f(hu.y), b2f(hu.z), b2f(hu.w) };
            #pragma unroll
            for (int r = 0; r < 4; ++r) {
                acc[r][0] = fmaf(hr[r], w0, acc[r][0]);
                acc[r][1] = fmaf(hr[r], w1, acc[r][1]);
                acc[r][2] = fmaf(hr[r], w2, acc[r][2]);
                acc[r][3] = fmaf(hr[r], w3, acc[r][3]);
            }
        }

        #pragma unroll
        for (int r = 0; r < 4; ++r) {
            int row = r0 + tr * 4 + r;
            if (row < N) {
                us4 u = { f2b(acc[r][0]), f2b(acc[r][1]), f2b(acc[r][2]), f2b(acc[r][3]) };
                *(us4*)(Whb + (size_t)row * CF + tc * 4) = u;
            }
        }

        int g = tc >> 3;
        int lane = tid & 63;
        #pragma unroll
        for (int r = 0; r < 4; ++r) {
            float ps = acc[r][0] * aS[tc*4] + acc[r][1] * aS[tc*4+1]
                     + acc[r][2] * aS[tc*4+2] + acc[r][3] * aS[tc*4+3];
            float pd = acc[r][0] * aD[tc*4] + acc[r][1] * aD[tc*4+1]
                     + acc[r][2] * aD[tc*4+2] + acc[r][3] * aD[tc*4+3];
            #pragma unroll
            for (int off = 1; off < 8; off <<= 1) {
                ps += __shfl_xor(ps, off);
                pd += __shfl_xor(pd, off);
            }
            if ((lane & 7) == 0) {
                int row = r0 + tr * 4 + r;
                if (row < N) {
                    ssrc[(size_t)row * HEADS + g] = ps;
                    sdst[(size_t)row * HEADS + g] = pd;
                }
            }
        }
    } else {
        // ----- edge path: deg count + edge-feature dot -----
        float* ae = (float*)smem;     // [4][16]
        if (tid < HEADS * EDGE_F) {
            int g = tid >> 4, j = tid & 15;
            ae[tid] = a[g * AROW + 2 * OUT_F + j];
        }
        __syncthreads();

        int e0 = (b - GB) * 1024 + tid * 4;
        if (e0 >= E) return;
        int n = (E - e0 < 4) ? (E - e0) : 4;

        if (n == 4) {
            int4 s4 = *(const int4*)(ei + e0);
            atomicAdd(&deg[s4.x], 1);
            atomicAdd(&deg[s4.y], 1);
            atomicAdd(&deg[s4.z], 1);
            atomicAdd(&deg[s4.w], 1);
        } else {
            for (int k = 0; k < n; ++k) atomicAdd(&deg[ei[e0 + k]], 1);
        }

        for (int k = 0; k < n; ++k) {
            int e = e0 + k;
            const float* eav = ea + (size_t)e * EDGE_F;
            float4 v0 = *(const float4*)(eav + 0);
            float4 v1 = *(const float4*)(eav + 4);
            float4 v2 = *(const float4*)(eav + 8);
            float4 v3 = *(const float4*)(eav + 12);
            float dv[HEADS];
            #pragma unroll
            for (int g = 0; g < HEADS; ++g) {
                const float* av = ae + g * EDGE_F;
                dv[g] = v0.x*av[0] + v0.y*av[1] + v0.z*av[2] + v0.w*av[3]
                      + v1.x*av[4] + v1.y*av[5] + v1.z*av[6] + v1.w*av[7]
                      + v2.x*av[8] + v2.y*av[9] + v2.z*av[10] + v2.w*av[11]
                      + v3.x*av[12] + v3.y*av[13] + v3.z*av[14] + v3.w*av[15];
            }
            edot4[e] = make_float4(dv[0], dv[1], dv[2], dv[3]);
        }
    }
}

// ---------------------------------------------------------------------------
// Kernel B: single-block shfl-based exclusive scan; writes off[] AND cursor[].
// ---------------------------------------------------------------------------
__global__ __launch_bounds__(1024) void k_scan(const int* __restrict__ deg,
                                               int* __restrict__ off,
                                               int* __restrict__ cursor, int N)
{
    __shared__ int wsum[16], wpre[17];
    int tid = threadIdx.x;
    int lane = tid & 63, wid = tid >> 6;
    int per = (N + 1023) / 1024;
    int base = tid * per;

    int local = 0;
    for (int j = 0; j < per; ++j) {
        int idx = base + j;
        if (idx < N) local += deg[idx];
    }
    int v = local;
    #pragma unroll
    for (int o = 1; o < 64; o <<= 1) {
        int u = __shfl_up(v, o);
        if (lane >= o) v += u;
    }
    if (lane == 63) wsum[wid] = v;
    __syncthreads();
    if (tid == 0) {
        int run = 0;
        for (int w = 0; w < 16; ++w) { wpre[w] = run; run += wsum[w]; }
        wpre[16] = run;
    }
    __syncthreads();
    int run = wpre[wid] + v - local;
    for (int j = 0; j < per; ++j) {
        int idx = base + j;
        if (idx < N) { off[idx] = run; cursor[idx] = run; run += deg[idx]; }
    }
    if (tid == 0) off[N] = wpre[16];
}

// ---------------------------------------------------------------------------
// Kernel C: softmax over heads + bin-by-src. 8-byte record per edge:
// bits[15:0]=dst, [27:16]=q0, [39:28]=q1, [51:40]=q2, [63:52]=q3
// (12-bit fixed-point attention weights). Two edges per thread.
// ---------------------------------------------------------------------------
static __device__ __forceinline__ u64 make_rec(int d, float4 s, float4 t, float4 ed)
{
    float e0 = s.x + t.x + ed.x;
    float e1 = s.y + t.y + ed.y;
    float e2 = s.z + t.z + ed.z;
    float e3 = s.w + t.w + ed.w;
    e0 = (e0 >= 0.f) ? e0 : ALPHA * e0;
    e1 = (e1 >= 0.f) ? e1 : ALPHA * e1;
    e2 = (e2 >= 0.f) ? e2 : ALPHA * e2;
    e3 = (e3 >= 0.f) ? e3 : ALPHA * e3;
    float m = fmaxf(fmaxf(e0, e1), fmaxf(e2, e3));
    float p0 = __expf(e0 - m), p1 = __expf(e1 - m);
    float p2 = __expf(e2 - m), p3 = __expf(e3 - m);
    float inv = 4095.f / (p0 + p1 + p2 + p3);
    unsigned q0 = (unsigned)(p0 * inv + 0.5f);
    unsigned q1 = (unsigned)(p1 * inv + 0.5f);
    unsigned q2 = (unsigned)(p2 * inv + 0.5f);
    unsigned q3 = (unsigned)(p3 * inv + 0.5f);
    return (u64)(unsigned)d | ((u64)q0 << 16) | ((u64)q1 << 28)
         | ((u64)q2 << 40) | ((u64)q3 << 52);
}

__global__ __launch_bounds__(256) void k_att_fill(const int* __restrict__ ei,
                                                  const float* __restrict__ ssrc,
                                                  const float* __restrict__ sdst,
                                                  const float4* __restrict__ edot4,
                                                  int* __restrict__ cursor,
                                                  u64* __restrict__ recs,
                                                  int E, int E2)
{
    int t = blockIdx.x * blockDim.x + threadIdx.x;
    if (t >= E2) return;
    int eA = t, eB = t + E2;
    bool hasB = (eB < E);
    int eBc = hasB ? eB : 0;

    int sA = ei[eA],  dA = ei[E + eA];
    int sB = ei[eBc], dB = ei[E + eBc];

    float4 saA = *(const float4*)(ssrc + (size_t)sA * HEADS);
    float4 sdA = *(const float4*)(sdst + (size_t)dA * HEADS);
    float4 edA = edot4[eA];
    float4 saB = *(const float4*)(ssrc + (size_t)sB * HEADS);
    float4 sdB = *(const float4*)(sdst + (size_t)dB * HEADS);
    float4 edB = edot4[eBc];

    u64 rA = make_rec(dA, saA, sdA, edA);
    int posA = atomicAdd(&cursor[sA], 1);
    recs[posA] = rA;
    if (hasB) {
        u64 rB = make_rec(dB, saB, sdB, edB);
        int posB = atomicAdd(&cursor[sB], 1);
        recs[posB] = rB;
    }
}

// ---------------------------------------------------------------------------
// Kernel D: per-node aggregation + fused ELU.
// One wave per node, split in half-waves: half processes edge i2+half;
// lane owns 4 channels (ushort4 loads). 4 edges in flight per iteration.
// ---------------------------------------------------------------------------
__global__ __launch_bounds__(256) void k_aggregate(const int* __restrict__ off,
                                                   const u64* __restrict__ recs,
                                                   const unsigned short* __restrict__ Whb,
                                                   float* __restrict__ out,
                                                   int N)
{
    int wave = threadIdx.x >> 6;
    int lane = threadIdx.x & 63;
    int node = blockIdx.x * 4 + wave;
    if (node >= N) return;

    int beg = off[node];
    int end = off[node + 1];
    int l = lane & 31;
    int half = lane >> 5;
    int c0 = l * 4;
    int hh = l >> 3;
    int sh = 16 + 12 * hh;

    float ac0 = 0.f, ac1 = 0.f, ac2 = 0.f, ac3 = 0.f;
    for (int i2 = beg; i2 < end; i2 += 4) {
        int iA = i2 + half;
        int iB = i2 + 2 + half;
        u64 rA = (iA < end) ? recs[iA] : 0ull;   // zero rec: att=0, dst=0 (safe)
        u64 rB = (iB < end) ? recs[iB] : 0ull;
        int dAi = (int)(rA & 0xFFFFu);
        int dBi = (int)(rB & 0xFFFFu);
        us4 wA = *(const us4*)(Whb + (size_t)dAi * CF + c0);
        us4 wB = *(const us4*)(Whb + (size_t)dBi * CF + c0);
        float atA = (float)((unsigned)((rA >> sh) & 0xFFFu)) * (1.f / 4095.f);
        float atB = (float)((unsigned)((rB >> sh) & 0xFFFu)) * (1.f / 4095.f);
        ac0 = fmaf(atA, b2f(wA.x), ac0);
        ac1 = fmaf(atA, b2f(wA.y), ac1);
        ac2 = fmaf(atA, b2f(wA.z), ac2);
        ac3 = fmaf(atA, b2f(wA.w), ac3);
        ac0 = fmaf(atB, b2f(wB.x), ac0);
        ac1 = fmaf(atB, b2f(wB.y), ac1);
        ac2 = fmaf(atB, b2f(wB.z), ac2);
        ac3 = fmaf(atB, b2f(wB.w), ac3);
    }
    ac0 += __shfl_xor(ac0, 32);
    ac1 += __shfl_xor(ac1, 32);
    ac2 += __shfl_xor(ac2, 32);
    ac3 += __shfl_xor(ac3, 32);

    if (half == 0) {
        ac0 = (ac0 > 0.f) ? ac0 : (__expf(ac0) - 1.f);
        ac1 = (ac1 > 0.f) ? ac1 : (__expf(ac1) - 1.f);
        ac2 = (ac2 > 0.f) ? ac2 : (__expf(ac2) - 1.f);
        ac3 = (ac3 > 0.f) ? ac3 : (__expf(ac3) - 1.f);
        *(float4*)(out + (size_t)node * CF + c0) = make_float4(ac0, ac1, ac2, ac3);
    }
}

extern "C" void kernel_launch(void* const* d_in, const int* in_sizes, int n_in,
                              void* d_out, int out_size, void* d_ws, size_t ws_size,
                              hipStream_t stream)
{
    const float* h  = (const float*)d_in[0];
    const int*   ei = (const int*)d_in[1];
    const float* ea = (const float*)d_in[2];
    const float* W  = (const float*)d_in[3];
    const float* a  = (const float*)d_in[4];
    float* out = (float*)d_out;

    int N = in_sizes[0] / IN_F;     // 20000
    int E = in_sizes[1] / 2;        // 640000

    char* ws = (char*)d_ws;
    float4*         edot4  = (float4*)ws;         ws += (size_t)E * sizeof(float4);
    u64*            recs   = (u64*)ws;            ws += (size_t)E * sizeof(u64);
    unsigned short* Whb    = (unsigned short*)ws; ws += (size_t)N * CF * sizeof(unsigned short);
    float*          ssrc   = (float*)ws;          ws += (size_t)N * HEADS * sizeof(float);
    float*          sdst   = (float*)ws;          ws += (size_t)N * HEADS * sizeof(float);
    int*            deg    = (int*)ws;            ws += (size_t)N * sizeof(int);
    int*            cursor = (int*)ws;            ws += (size_t)N * sizeof(int);
    int*            off    = (int*)ws;            ws += (size_t)(N + 1) * sizeof(int);

    hipMemsetAsync(deg, 0, (size_t)N * sizeof(int), stream);

    int GB = (N + BM - 1) / BM;          // 625 gemm blocks
    int CB = (E + 1023) / 1024;          // 625 edge blocks
    k_fused<<<GB + CB, 256, 0, stream>>>(h, W, a, ei, ea, Whb, ssrc, sdst,
                                         edot4, deg, N, E, GB);
    k_scan<<<1, 1024, 0, stream>>>(deg, off, cursor, N);
    int E2 = (E + 1) >> 1;
    k_att_fill<<<(E2 + 255) / 256, 256, 0, stream>>>(ei, ssrc, sdst, edot4,
                                                     cursor, recs, E, E2);
    k_aggregate<<<(N + 3) / 4, 256, 0, stream>>>(off, recs, Whb, out, N);
}